// Round 8
// baseline (574.900 us; speedup 1.0000x reference)
//
#include <hip/hip_runtime.h>

// Problem dims
#define B_  4096
#define T_  128
#define NL  256
#define NS  64
#define NO  32
#define V_  64
#define RB  32            // rows per block
#define NBLK (B_ / RB)    // 128 blocks

typedef __bf16 bf16;
typedef bf16  bf16x8 __attribute__((ext_vector_type(8)));
typedef bf16  bf16x4 __attribute__((ext_vector_type(4)));
typedef float f32x4  __attribute__((ext_vector_type(4)));

#define MF(a, b, c) __builtin_amdgcn_mfma_f32_16x16x32_bf16(a, b, c, 0, 0, 0)

// lgkm-only barrier: block communication is exclusively via LDS.
#define LGKM_BARRIER() asm volatile("s_waitcnt lgkmcnt(0)\n\ts_barrier" ::: "memory")

// Manual load into the wave's vmcnt FIFO (flat-global, per-lane 64b addr,
// 13-bit signed immediate offset).
#define GLOAD(dst, ptr, off) \
    asm volatile("global_load_dwordx4 %0, %1, off offset:" #off \
                 : "=v"(dst) : "v"(ptr))

// ---------------------------------------------------------------------------
// Split fp32 weights -> bf16 hi/lo planes in MFMA A-fragment order.
// ---------------------------------------------------------------------------
template <int TSHIFT>
__global__ void split_w_frag(const float* __restrict__ src,
                             bf16* __restrict__ hi, bf16* __restrict__ lo,
                             int total4) {
    int t4 = blockIdx.x * blockDim.x + threadIdx.x;
    if (t4 >= total4) return;
    const int jb   = (t4 & 1) * 4;
    const int L    = (t4 >> 1) & 63;
    const int ks   = (t4 >> 7) & 7;
    const int rest = t4 >> 10;
    const int t    = rest & ((1 << TSHIFT) - 1);
    const int s    = rest >> TSHIFT;
    const int row  = ((s << TSHIFT) + t) * 16 + (L & 15);
    const int k    = ks * 32 + (L >> 4) * 8 + jb;
    const float4 v = *(const float4*)(src + (size_t)row * NL + k);
    float vv[4] = {v.x, v.y, v.z, v.w};
    bf16x4 h, l;
#pragma unroll
    for (int e = 0; e < 4; e++) {
        bf16 hh = (bf16)vv[e];
        h[e] = hh;
        l[e] = (bf16)(vv[e] - (float)hh);
    }
    *(bf16x4*)(hi + (size_t)t4 * 4) = h;
    *(bf16x4*)(lo + (size_t)t4 * 4) = l;
}

// inv[s][v] = last j with out_idx[s][j]==v, else -1 (numpy last-dup-wins)
__global__ void inv_kernel(const int* __restrict__ out_idx, int* __restrict__ inv) {
    int t = blockIdx.x * blockDim.x + threadIdx.x;
    if (t >= NS * V_) return;
    int s = t >> 6, v = t & 63;
    int jf = -1;
#pragma unroll
    for (int j = 0; j < NO; j++)
        if (out_idx[(s << 5) | j] == v) jf = j;
    inv[t] = jf;
}

__device__ __forceinline__ float fast_tanh(float z) {
    float e = __expf(2.0f * z);
    return 1.0f - 2.0f / (e + 1.0f);
}

// x fragment-order address, 32-row layout: slice ks has 1024 elems
// (rh0 512 then rh1 512). col c = t*16 + q*4 + e, row = n + rh*16.
__device__ __forceinline__ int xaddr32(int t, int q, int n, int rh) {
    return (t >> 1) * 1024 + rh * 512 + ((t & 1) * 2 + (q >> 1)) * 128 + n * 8 + (q & 1) * 4;
}

// ---------------------------------------------------------------------------
// Persistent per-block recurrence, 128 blocks x 16 waves, 1 block/CU.
// RB=32: every W1/W2 fragment feeds TWO row-half B-fragments -> aggregate
// weight traffic halves vs RB=16 (tests the shared-L2/fabric-BW hypothesis).
//
// W1 pipeline = 4-slot HALF-STEP ring (slot = slice&3, 32 VGPR pinned):
//   slice c consumes slot c&3, then reissues into the same slot the load
//   consumed 4 slices later (slices 0-3 load THIS step's slices 4-7 from
//   cb*; slices 4-7 load NEXT step's slices 0-3 from nb*). Bases point at
//   slice 4 so all 8 slices fit the 13-bit signed immediate (-4096..+3072).
// W2 (4 frags) and b1 keep full-step distance.
//
// Per-step issue order: b1, W1 x16 (slice order), W2 x4, [out store].
// Exact counted waits (in-order vmcnt retirement):
//   slices 0-3: younger = 11(+store)  -> vmcnt(11)
//   slices 4-7: younger = 6           -> vmcnt(5)
//   GEMM2:      younger = 17(+store)  -> vmcnt(17)
//   tanh (b1):  younger = 20          -> vmcnt(20)
//   tails: vmcnt(0).
// ---------------------------------------------------------------------------
__launch_bounds__(1024, 4)
__global__ void lalr_main(const float* __restrict__ latent0,
                          const float* __restrict__ b1,
                          const float* __restrict__ b2,
                          const int*   __restrict__ state_seq,
                          const int*   __restrict__ inv,
                          const bf16*  __restrict__ W1h, const bf16* __restrict__ W1l,
                          const bf16*  __restrict__ W2h, const bf16* __restrict__ W2l,
                          float* __restrict__ out) {
    __shared__ bf16  xh[2][8192];        // 32 KB
    __shared__ bf16  xl[2][8192];        // 32 KB
    __shared__ float Sp[2][4][32][36];   // 36 KB  GEMM2 K-partials (pad 36)
    __shared__ float b2s[NS * NO];       //  8 KB
    __shared__ int   invs[NS * V_];      // 16 KB
    __shared__ int   sseq[T_];           // 0.5 KB   total 127,488 B

    const int tid  = threadIdx.x;
    const int wave = tid >> 6;           // 0..15
    const int lane = tid & 63;
    const int n    = lane & 15;          // batch row (within half)
    const int q    = lane >> 4;          // quad
    const int r0   = blockIdx.x * RB;
    const int t2   = wave & 1;           // GEMM2 col-tile
    const int rh2  = (wave >> 1) & 1;    // GEMM2 row-half
    const int kp   = wave >> 2;          // GEMM2 K-part (0..3): slices 2kp, 2kp+1
    const int sa   = 2 * kp;

    // ---- stage uniforms into LDS (prologue-only plain global traffic) ----
    if (tid < NS * NO / 4) ((float4*)b2s)[tid] = ((const float4*)b2)[tid];
    if (tid < NS * V_ / 4) ((int4*)invs)[tid] = ((const int4*)inv)[tid];
    if (tid < T_) sseq[tid] = state_seq[tid];

    // ---- init: latent0 -> x[0] fragments (both row-halves) ----
    {
        const float* pa = latent0 + (size_t)(r0 + n) * NL + wave * 16 + q * 4;
        float4 va = *(const float4*)pa;
        float4 vb = *(const float4*)(pa + 16 * NL);   // row n+16
        float fa[4] = {va.x, va.y, va.z, va.w};
        float fb[4] = {vb.x, vb.y, vb.z, vb.w};
        bf16x4 hva, lva, hvb, lvb;
#pragma unroll
        for (int e = 0; e < 4; e++) {
            bf16 ha = (bf16)fa[e]; hva[e] = ha; lva[e] = (bf16)(fa[e] - (float)ha);
            bf16 hb = (bf16)fb[e]; hvb[e] = hb; lvb[e] = (bf16)(fb[e] - (float)hb);
        }
        const int a0 = xaddr32(wave, q, n, 0);
        const int a1 = xaddr32(wave, q, n, 1);
        *(bf16x4*)(&xh[0][a0]) = hva; *(bf16x4*)(&xl[0][a0]) = lva;
        *(bf16x4*)(&xh[0][a1]) = hvb; *(bf16x4*)(&xl[0][a1]) = lvb;
    }

    int s0 = state_seq[0], s1 = -1, s2 = -1;

    // Ring slots (4 x hi/lo = 32 VGPR) + W2 (16) + b1 (4).
    bf16x8 pwh0, pwh1, pwh2, pwh3;
    bf16x8 pwl0, pwl1, pwl2, pwl3;
    bf16x8 w2ha, w2la, w2hb, w2lb;
    f32x4  b1v;

    const size_t wfrag = (size_t)wave * 8 * 512 + lane * 8;  // per-wave/lane W1 offset

    // Prologue: L(0, slices 0..3) + W2 placeholder, in consumption order.
    {
        const bf16* cbh = W1h + (size_t)s0 * 16 * 8 * 512 + wfrag + 4 * 512;
        const bf16* cbl = W1l + (size_t)s0 * 16 * 8 * 512 + wfrag + 4 * 512;
        GLOAD(pwh0, cbh, -4096); GLOAD(pwl0, cbl, -4096);
        GLOAD(pwh1, cbh, -3072); GLOAD(pwl1, cbl, -3072);
        GLOAD(pwh2, cbh, -2048); GLOAD(pwl2, cbl, -2048);
        GLOAD(pwh3, cbh, -1024); GLOAD(pwl3, cbl, -1024);
        const bf16* c2h = W2h + (size_t)((s0 * 2 + t2) * 8 + sa) * 512 + lane * 8;
        const bf16* c2l = W2l + (size_t)((s0 * 2 + t2) * 8 + sa) * 512 + lane * 8;
        GLOAD(w2ha, c2h, 0);    GLOAD(w2la, c2l, 0);
        GLOAD(w2hb, c2h, 1024); GLOAD(w2lb, c2l, 1024);
    }

    LGKM_BARRIER();      // x[0]/staging visible; weight loads stay in flight

// One GEMM1 slice c using ring slot s: 4 LDS x reads, counted wait, fence,
// 6 MFMA (two row-half acc chains), reissue slot from base BH/BL at OFF.
#define G1S(c, s, BH, BL, OFF, CNT) {                                       \
        bf16x8 xa0 = *(const bf16x8*)(xbh + (c) * 1024);                    \
        bf16x8 xb0 = *(const bf16x8*)(xbl + (c) * 1024);                    \
        bf16x8 xa1 = *(const bf16x8*)(xbh + (c) * 1024 + 512);              \
        bf16x8 xb1 = *(const bf16x8*)(xbl + (c) * 1024 + 512);              \
        asm volatile("s_waitcnt vmcnt(" #CNT ")" ::: "memory");             \
        __builtin_amdgcn_sched_barrier(0);                                  \
        acc1a = MF(pwh##s, xa0, acc1a);                                     \
        acc1b = MF(pwh##s, xa1, acc1b);                                     \
        acc1a = MF(pwl##s, xa0, acc1a);                                     \
        acc1b = MF(pwl##s, xa1, acc1b);                                     \
        acc1a = MF(pwh##s, xb0, acc1a);                                     \
        acc1b = MF(pwh##s, xb1, acc1b);                                     \
        GLOAD(pwh##s, BH, OFF);                                             \
        GLOAD(pwl##s, BL, OFF);                                             \
    }

    for (int i = 0; i <= T_ + 1; i++) {
        const int ib  = i & 1;
        const int cur = ib;

        const int ns0 = (i + 1 < T_) ? sseq[i + 1] : -1;
        const int ls  = (ns0 >= 0) ? ns0 : 0;   // dummy state keeps FIFO shape
        // bases point at slice 4 of the respective state
        const bf16* cbh = W1h + (size_t)s0 * 16 * 8 * 512 + wfrag + 2048;
        const bf16* cbl = W1l + (size_t)s0 * 16 * 8 * 512 + wfrag + 2048;
        const bf16* nbh = W1h + (size_t)ls * 16 * 8 * 512 + wfrag + 2048;
        const bf16* nbl = W1l + (size_t)ls * 16 * 8 * 512 + wfrag + 2048;
        const bf16* xbh = &xh[cur][lane * 8];
        const bf16* xbl = &xl[cur][lane * 8];

        // ---- b1 for THIS step rides the FIFO (consumed at tanh) ----
        if (s0 >= 0) {
            const float* pb1 = b1 + (size_t)s0 * NL + wave * 16 + q * 4;
            GLOAD(b1v, pb1, 0);
        }

        // ---- GEMM1 (state s0): 32 rows x 16 cols/wave, K=256 ----
        f32x4 acc1a, acc1b;
        if (s0 >= 0) {
            acc1a = (f32x4){0.f, 0.f, 0.f, 0.f};
            acc1b = (f32x4){0.f, 0.f, 0.f, 0.f};
            G1S(0, 0, cbh, cbl, 0,     11)   // issue this-step slice 4
            G1S(1, 1, cbh, cbl, 1024,  11)   //   "      "     slice 5
            G1S(2, 2, cbh, cbl, 2048,  11)   //   "      "     slice 6
            G1S(3, 3, cbh, cbl, 3072,  11)   //   "      "     slice 7
            G1S(4, 0, nbh, nbl, -4096, 5)    // issue next-step slice 0
            G1S(5, 1, nbh, nbl, -3072, 5)    //   "      "      slice 1
            G1S(6, 2, nbh, nbl, -2048, 5)    //   "      "      slice 2
            G1S(7, 3, nbh, nbl, -1024, 5)    //   "      "      slice 3
        }

        // ---- GEMM2 (state s1): task (t2, rh2, kp) = 16x16, K=64 ----
        if (s1 >= 0) {
            const bf16* g2h = xbh + sa * 1024 + rh2 * 512;
            const bf16* g2l = xbl + sa * 1024 + rh2 * 512;
            bf16x8 xa0 = *(const bf16x8*)(g2h);
            bf16x8 xb0 = *(const bf16x8*)(g2l);
            bf16x8 xa1 = *(const bf16x8*)(g2h + 1024);
            bf16x8 xb1 = *(const bf16x8*)(g2l + 1024);
            if (s0 >= 0) {
                asm volatile("s_waitcnt vmcnt(17)" ::: "memory");
            } else {
                asm volatile("s_waitcnt vmcnt(0)" ::: "memory");   // tail drain
            }
            __builtin_amdgcn_sched_barrier(0);
            f32x4 a2 = (f32x4){0.f, 0.f, 0.f, 0.f};
            a2 = MF(w2ha, xa0, a2);
            a2 = MF(w2la, xa0, a2);
            a2 = MF(w2ha, xb0, a2);
            a2 = MF(w2hb, xa1, a2);
            a2 = MF(w2lb, xa1, a2);
            a2 = MF(w2hb, xb1, a2);
            if (kp == 0) {
                float4 bb = *(const float4*)(&b2s[s1 * NO + t2 * 16 + q * 4]);
                a2[0] += bb.x; a2[1] += bb.y; a2[2] += bb.z; a2[3] += bb.w;
            }
            *(f32x4*)(&Sp[ib][kp][rh2 * 16 + n][t2 * 16 + q * 4]) = a2;
        }
        if (s0 >= 0) {   // reissue W2 for next iteration (state = current s0)
            const bf16* n2h = W2h + (size_t)((s0 * 2 + t2) * 8 + sa) * 512 + lane * 8;
            const bf16* n2l = W2l + (size_t)((s0 * 2 + t2) * 8 + sa) * 512 + lane * 8;
            GLOAD(w2ha, n2h, 0);
            GLOAD(w2la, n2l, 0);
            GLOAD(w2hb, n2h, 1024);
            GLOAD(w2lb, n2l, 1024);
        }

        // ---- tanh + hi/lo split -> x[cur^1] (both row-halves) ----
        if (s0 >= 0) {
            asm volatile("s_waitcnt vmcnt(20)" ::: "memory");   // retire b1v
            __builtin_amdgcn_sched_barrier(0);
            bf16x4 hva, lva, hvb, lvb;
#pragma unroll
            for (int e = 0; e < 4; e++) {
                float ha = fast_tanh(acc1a[e] + b1v[e]);
                bf16 hh = (bf16)ha;
                hva[e] = hh; lva[e] = (bf16)(ha - (float)hh);
                float hb = fast_tanh(acc1b[e] + b1v[e]);
                bf16 hh2 = (bf16)hb;
                hvb[e] = hh2; lvb[e] = (bf16)(hb - (float)hh2);
            }
            const int a0 = xaddr32(wave, q, n, 0);
            const int a1 = xaddr32(wave, q, n, 1);
            *(bf16x4*)(&xh[cur ^ 1][a0]) = hva; *(bf16x4*)(&xl[cur ^ 1][a0]) = lva;
            *(bf16x4*)(&xh[cur ^ 1][a1]) = hvb; *(bf16x4*)(&xl[cur ^ 1][a1]) = lvb;
        }

        // ---- softmax + shfl-scatter + store for step i-2 (waves 0-7) ----
        if (s2 >= 0 && tid < 512) {
            const int r  = tid >> 4;         // 0..31
            const int j0 = tid & 15;
            const int pb = (i - 1) & 1;
            float v0 = 0.f, v1 = 0.f;
#pragma unroll
            for (int kq = 0; kq < 4; kq++) {
                v0 += Sp[pb][kq][r][j0];
                v1 += Sp[pb][kq][r][j0 + 16];
            }
            float m = fmaxf(v0, v1);
#pragma unroll
            for (int d = 1; d < 16; d <<= 1) m = fmaxf(m, __shfl_xor(m, d));
            float e0 = __expf(v0 - m), e1 = __expf(v1 - m);
            float su = e0 + e1;
#pragma unroll
            for (int d = 1; d < 16; d <<= 1) su += __shfl_xor(su, d);
            float is = 1.0f / su;
            float p0 = e0 * is, p1 = e1 * is;
            const int gb = lane & 48;     // 16-lane group base
            int4 iv4 = *(const int4*)(&invs[s2 * V_ + j0 * 4]);
            int ivv[4] = {iv4.x, iv4.y, iv4.z, iv4.w};
            float o[4];
#pragma unroll
            for (int e = 0; e < 4; e++) {
                float ga = __shfl(p0, gb + (ivv[e] & 15));
                float gc = __shfl(p1, gb + (ivv[e] & 15));
                o[e] = (ivv[e] < 0) ? 0.f : ((ivv[e] < 16) ? ga : gc);
            }
            *(float4*)(out + ((size_t)(r0 + r) * T_ + (i - 2)) * V_ + j0 * 4) = *(float4*)o;
        }

        s2 = s1; s1 = s0; s0 = ns0;
        LGKM_BARRIER();
    }
#undef G1S
}

extern "C" void kernel_launch(void* const* d_in, const int* in_sizes, int n_in,
                              void* d_out, int out_size, void* d_ws, size_t ws_size,
                              hipStream_t stream) {
    const float* latent0   = (const float*)d_in[0];
    const float* W1        = (const float*)d_in[1];
    const float* b1        = (const float*)d_in[2];
    const float* W2        = (const float*)d_in[3];
    const float* b2        = (const float*)d_in[4];
    const int*   state_seq = (const int*)d_in[5];
    const int*   out_idx   = (const int*)d_in[6];
    float* out = (float*)d_out;

    bf16* W1h = (bf16*)d_ws;
    bf16* W1l = W1h + (size_t)NS * NL * NL;
    bf16* W2h = W1l + (size_t)NS * NL * NL;
    bf16* W2l = W2h + (size_t)NS * NO * NL;
    int*  inv = (int*)(W2l + (size_t)NS * NO * NL);

    const int n4_w1 = NS * NL * NL / 4;   // 1,048,576
    const int n4_w2 = NS * NO * NL / 4;   // 131,072
    split_w_frag<4><<<n4_w1 / 256, 256, 0, stream>>>(W1, W1h, W1l, n4_w1);
    split_w_frag<1><<<n4_w2 / 256, 256, 0, stream>>>(W2, W2h, W2l, n4_w2);
    inv_kernel<<<(NS * V_ + 255) / 256, 256, 0, stream>>>(out_idx, inv);

    lalr_main<<<NBLK, 1024, 0, stream>>>(latent0, b1, b2, state_seq, inv,
                                         W1h, W1l, W2h, W2l, out);
}

// Round 9
// 574.140 us; speedup vs baseline: 1.0013x; 1.0013x over previous
//
#include <hip/hip_runtime.h>

// Problem dims
#define B_  4096
#define T_  128
#define NL  256
#define NS  64
#define NO  32
#define V_  64
#define RB  16            // rows per block
#define NBLK (B_ / RB)    // 256 blocks

typedef _Float16 f16;
typedef f16   f16x8 __attribute__((ext_vector_type(8)));
typedef f16   f16x4 __attribute__((ext_vector_type(4)));
typedef int   ix2   __attribute__((ext_vector_type(2)));
typedef float f32x4 __attribute__((ext_vector_type(4)));

#define MF(a, b, c) __builtin_amdgcn_mfma_f32_16x16x32_f16(a, b, c, 0, 0, 0)

// lgkm-only barrier: block communication is exclusively via LDS.
#define LGKM_BARRIER() asm volatile("s_waitcnt lgkmcnt(0)\n\ts_barrier" ::: "memory")

// Manual loads into the wave's vmcnt FIFO (flat-global, per-lane 64b addr).
#define GLOAD4(dst, ptr) \
    asm volatile("global_load_dwordx4 %0, %1, off" : "=v"(dst) : "v"(ptr))
#define GLOADQ(dst, ptr) \
    asm volatile("global_load_dwordx2 %0, %1, off" : "=v"(dst) : "v"(ptr))

// ---------------------------------------------------------------------------
// Split fp32 weights -> fp16 hi plane + int8 lo plane (fixed scale 2^-20),
// both in MFMA A-fragment order:
//   elem idx = (((s*NT + t)*8 + ks)*512) + L*8 + j
//   maps to  W[s][t*16 + (L&15)][ks*32 + (L>>4)*8 + j]
// |w| <= ~0.35 (N(0,1)/16) -> fp16 ulp <= 2^-12 -> |lo| <= 2^-13 -> q <= 64.
// Quantization error 2^-21 absolute: better than the old bf16 hi/lo pair.
// ---------------------------------------------------------------------------
template <int TSHIFT>
__global__ void split_w_frag(const float* __restrict__ src,
                             f16* __restrict__ hi, char* __restrict__ qlo,
                             int total4) {
    int t4 = blockIdx.x * blockDim.x + threadIdx.x;
    if (t4 >= total4) return;
    const int jb   = (t4 & 1) * 4;
    const int L    = (t4 >> 1) & 63;
    const int ks   = (t4 >> 7) & 7;
    const int rest = t4 >> 10;
    const int t    = rest & ((1 << TSHIFT) - 1);
    const int s    = rest >> TSHIFT;
    const int row  = ((s << TSHIFT) + t) * 16 + (L & 15);
    const int k    = ks * 32 + (L >> 4) * 8 + jb;
    const float4 v = *(const float4*)(src + (size_t)row * NL + k);
    float vv[4] = {v.x, v.y, v.z, v.w};
    f16x4 h;
    int qb = 0;
#pragma unroll
    for (int e = 0; e < 4; e++) {
        f16 hh = (f16)vv[e];
        h[e] = hh;
        float lo = vv[e] - (float)hh;
        float qf = fminf(fmaxf(rintf(lo * 0x1p20f), -127.f), 127.f);
        qb |= (((int)qf) & 0xff) << (8 * e);
    }
    *(f16x4*)(hi + (size_t)t4 * 4) = h;
    ((int*)qlo)[t4] = qb;
}

// inv[s][v] = last j with out_idx[s][j]==v, else -1 (numpy last-dup-wins)
__global__ void inv_kernel(const int* __restrict__ out_idx, int* __restrict__ inv) {
    int t = blockIdx.x * blockDim.x + threadIdx.x;
    if (t >= NS * V_) return;
    int s = t >> 6, v = t & 63;
    int jf = -1;
#pragma unroll
    for (int j = 0; j < NO; j++)
        if (out_idx[(s << 5) | j] == v) jf = j;
    inv[t] = jf;
}

__device__ __forceinline__ float fast_tanh(float z) {
    float e = __expf(2.0f * z);
    return 1.0f - 2.0f / (e + 1.0f);
}

// int8-packed lo fragment -> fp16x8 (scale 2^-20).
__device__ __forceinline__ f16x8 unpack_q(ix2 qd) {
    f16x8 r;
#pragma unroll
    for (int j = 0; j < 4; j++) {
        int b0 = (int)(signed char)((qd[0] >> (8 * j)) & 0xff);
        int b1 = (int)(signed char)((qd[1] >> (8 * j)) & 0xff);
        r[j]     = (f16)((float)b0 * 0x1p-20f);
        r[j + 4] = (f16)((float)b1 * 0x1p-20f);
    }
    return r;
}

// x fragment-order address for element (batch row n, k = t*16 + q*4):
__device__ __forceinline__ int xaddr(int t, int q, int n) {
    return ((t >> 1) * 512) + (((t & 1) * 2 + (q >> 1)) * 128) + n * 8 + (q & 1) * 4;
}

// ---------------------------------------------------------------------------
// Persistent per-block recurrence, 256 blocks x 16 waves, 1 block/CU.
// Weight stream is 3 B/weight (fp16 hi dwordx4 + int8 lo dwordx2): per-CU
// 216 KB/step vs 288 KB for the bf16 hi/lo pair -- attacks the measured
// per-CU delivery cap (~35 B/cy, invariant across rounds 0-8).
// FIFO/step/wave = 8x(W1 hi,lo) + (W2 hi,lo) = 18 ops (+<=1 out store).
// At slice-ks wait: younger = 2(7-ks) + 2 + 2ks = 16 -> vmcnt(16) uniform;
// GEMM2 wait: younger = 16 W1 reissues -> vmcnt(16); tails vmcnt(0).
// Waits TIE the consumed regs ("+v") so the VALU unpack cannot be hoisted
// above the wait (rule-18: "memory" doesn't order register-only ops).
// Rotation (blockIdx>>3)&7 de-syncs same-XCD streams (+1.6%, round 6).
// ---------------------------------------------------------------------------
__launch_bounds__(1024, 4)
__global__ void lalr_main(const float* __restrict__ latent0,
                          const float* __restrict__ b1,
                          const float* __restrict__ b2,
                          const int*   __restrict__ state_seq,
                          const int*   __restrict__ inv,
                          const f16*   __restrict__ W1F, const char* __restrict__ W1Q,
                          const f16*   __restrict__ W2F, const char* __restrict__ W2Q,
                          float* __restrict__ out) {
    __shared__ f16   xh[2][4096];        // 16 KB  (frag order, double buffered)
    __shared__ f16   xl[2][4096];        // 16 KB
    __shared__ float Sp[2][8][16][36];   // 36 KB  GEMM2 K-partials (pad 36)
    __shared__ float b1s[NS * NL];       // 64 KB
    __shared__ float b2s[NS * NO];       //  8 KB
    __shared__ int   invs[NS * V_];      // 16 KB
    __shared__ int   sseq[T_];           // 0.5 KB   total 160,256 B

    const int tid  = threadIdx.x;
    const int wave = tid >> 6;           // 0..15
    const int lane = tid & 63;
    const int n    = lane & 15;          // batch row
    const int q    = lane >> 4;          // quad
    const int r0   = blockIdx.x * RB;
    const int t2   = wave & 1;           // GEMM2 col-tile
    const int ks2  = wave >> 1;          // GEMM2 K-slice

    // Rotated GEMM1 slice visit order (block-uniform).
    const int rot = (blockIdx.x >> 3) & 7;
    const int rs0 = (0 + rot) & 7, rs1 = (1 + rot) & 7, rs2 = (2 + rot) & 7,
              rs3 = (3 + rot) & 7, rs4 = (4 + rot) & 7, rs5 = (5 + rot) & 7,
              rs6 = (6 + rot) & 7, rs7 = (7 + rot) & 7;

    // ---- stage uniforms into LDS (prologue-only plain global traffic) ----
    for (int k = tid; k < NS * NL / 4; k += 1024)
        ((float4*)b1s)[k] = ((const float4*)b1)[k];
    if (tid < NS * NO / 4) ((float4*)b2s)[tid] = ((const float4*)b2)[tid];
    if (tid < NS * V_ / 4) ((int4*)invs)[tid] = ((const int4*)inv)[tid];
    if (tid < T_) sseq[tid] = state_seq[tid];

    // ---- init: latent0 -> x[0] fp16 hi/lo fragments ----
    {
        float4 v = *(const float4*)(latent0 + (size_t)(r0 + n) * NL + wave * 16 + q * 4);
        float vv[4] = {v.x, v.y, v.z, v.w};
        f16x4 hv, lv;
#pragma unroll
        for (int e = 0; e < 4; e++) {
            f16 hh = (f16)vv[e];
            hv[e] = hh;
            lv[e] = (f16)(vv[e] - (float)hh);
        }
        const int a = xaddr(wave, q, n);
        *(f16x4*)(&xh[0][a]) = hv;
        *(f16x4*)(&xl[0][a]) = lv;
    }

    int s0 = state_seq[0], s1 = -1, s2 = -1;

    // FIFO destination registers: 8x (f16x8 hi + ix2 lo) + W2 pair.
    f16x8 pwh0, pwh1, pwh2, pwh3, pwh4, pwh5, pwh6, pwh7;
    ix2   pwq0, pwq1, pwq2, pwq3, pwq4, pwq5, pwq6, pwq7;
    f16x8 w2h2;
    ix2   w2q2;

    const int wfrag = wave * 4096 + lane * 8;   // elem (hi) == byte (lo) offset

    // Prologue: issue L_0 in exact (rotated) consumption order, 18 ops.
    {
        const f16*  h0 = W1F + (size_t)s0 * 65536 + wfrag;
        const char* q0 = W1Q + (size_t)s0 * 65536 + wfrag;
        GLOAD4(pwh0, h0 + rs0 * 512); GLOADQ(pwq0, q0 + rs0 * 512);
        GLOAD4(pwh1, h0 + rs1 * 512); GLOADQ(pwq1, q0 + rs1 * 512);
        GLOAD4(pwh2, h0 + rs2 * 512); GLOADQ(pwq2, q0 + rs2 * 512);
        GLOAD4(pwh3, h0 + rs3 * 512); GLOADQ(pwq3, q0 + rs3 * 512);
        GLOAD4(pwh4, h0 + rs4 * 512); GLOADQ(pwq4, q0 + rs4 * 512);
        GLOAD4(pwh5, h0 + rs5 * 512); GLOADQ(pwq5, q0 + rs5 * 512);
        GLOAD4(pwh6, h0 + rs6 * 512); GLOADQ(pwq6, q0 + rs6 * 512);
        GLOAD4(pwh7, h0 + rs7 * 512); GLOADQ(pwq7, q0 + rs7 * 512);
        const f16*  c2h = W2F + (size_t)((s0 * 2 + t2) * 8 + ks2) * 512 + lane * 8;
        const char* c2q = W2Q + (size_t)((s0 * 2 + t2) * 8 + ks2) * 512 + lane * 8;
        GLOAD4(w2h2, c2h); GLOADQ(w2q2, c2q);   // placeholder (iter-0 GEMM2 skipped)
    }

    LGKM_BARRIER();      // x[0]/staging visible; weight loads stay in flight

// One GEMM1 slice (rotated physical slice rs): LDS x reads, tied counted
// wait, fence, unpack + 3 MFMA, reissue hi/lo pair for next step.
#define G1S(ks, rs) {                                                       \
        const int xo = (rs) * 512 + lane * 8;                               \
        f16x8 xa = *(const f16x8*)(&xh[cur][xo]);                           \
        f16x8 xb = *(const f16x8*)(&xl[cur][xo]);                           \
        asm volatile("s_waitcnt vmcnt(16)"                                  \
                     : "+v"(pwh##ks), "+v"(pwq##ks) :: "memory");           \
        __builtin_amdgcn_sched_barrier(0);                                  \
        acc1 = MF(pwh##ks, xa, acc1);                                       \
        f16x8 wl = unpack_q(pwq##ks);                                       \
        acc1 = MF(wl, xa, acc1);                                            \
        acc1 = MF(pwh##ks, xb, acc1);                                       \
        GLOAD4(pwh##ks, nh0 + (rs) * 512);                                  \
        GLOADQ(pwq##ks, nq0 + (rs) * 512);                                  \
    }

    for (int i = 0; i <= T_ + 1; i++) {
        const int ib  = i & 1;
        const int cur = ib;

        // next-step W1 base pointers (dummy state 0 in tail keeps FIFO shape)
        const int ns0 = (i + 1 < T_) ? sseq[i + 1] : -1;
        const int ls  = (ns0 >= 0) ? ns0 : 0;
        const f16*  nh0 = W1F + (size_t)ls * 65536 + wfrag;
        const char* nq0 = W1Q + (size_t)ls * 65536 + wfrag;

        // ---- GEMM1 (state s0): full K=256, vmcnt-paced, rotated slices ----
        f32x4 acc1;
        if (s0 >= 0) {
            acc1 = (f32x4){0.f, 0.f, 0.f, 0.f};
            G1S(0, rs0)
            G1S(1, rs1)
            G1S(2, rs2)
            G1S(3, rs3)
            G1S(4, rs4)
            G1S(5, rs5)
            G1S(6, rs6)
            G1S(7, rs7)
        }

        // ---- GEMM2 (state s1): task (t2, ks2) ----
        if (s1 >= 0) {
            const int xo2 = ks2 * 512 + lane * 8;
            f16x8 xa = *(const f16x8*)(&xh[cur][xo2]);
            f16x8 xb = *(const f16x8*)(&xl[cur][xo2]);
            if (s0 >= 0) {
                asm volatile("s_waitcnt vmcnt(16)"
                             : "+v"(w2h2), "+v"(w2q2) :: "memory");
            } else {
                // tail: GEMM1 skipped -> no W1 reissues ahead; drain
                asm volatile("s_waitcnt vmcnt(0)"
                             : "+v"(w2h2), "+v"(w2q2) :: "memory");
            }
            __builtin_amdgcn_sched_barrier(0);
            f32x4 a2 = (f32x4){0.f, 0.f, 0.f, 0.f};
            a2 = MF(w2h2, xa, a2);
            f16x8 wl2 = unpack_q(w2q2);
            a2 = MF(wl2, xa, a2);
            a2 = MF(w2h2, xb, a2);
            if (ks2 == 0) {
                float4 bb = *(const float4*)(&b2s[s1 * NO + t2 * 16 + q * 4]);
                a2[0] += bb.x; a2[1] += bb.y; a2[2] += bb.z; a2[3] += bb.w;
            }
            *(f32x4*)(&Sp[ib][ks2][n][t2 * 16 + q * 4]) = a2;
        }
        if (s0 >= 0) {   // reissue W2 pair for next iteration (state = current s0)
            const f16*  n2h = W2F + (size_t)((s0 * 2 + t2) * 8 + ks2) * 512 + lane * 8;
            const char* n2q = W2Q + (size_t)((s0 * 2 + t2) * 8 + ks2) * 512 + lane * 8;
            GLOAD4(w2h2, n2h);
            GLOADQ(w2q2, n2q);
        }

        // ---- softmax + shfl-scatter + store for step i-2 (first 4 waves) ----
        if (s2 >= 0 && tid < 256) {
            const int r  = tid >> 4;
            const int j0 = tid & 15;
            const int pb = (i - 1) & 1;
            float v0 = 0.f, v1 = 0.f;
#pragma unroll
            for (int w = 0; w < 8; w++) {
                v0 += Sp[pb][w][r][j0];
                v1 += Sp[pb][w][r][j0 + 16];
            }
            float m = fmaxf(v0, v1);
#pragma unroll
            for (int d = 1; d < 16; d <<= 1) m = fmaxf(m, __shfl_xor(m, d));
            float e0 = __expf(v0 - m), e1 = __expf(v1 - m);
            float su = e0 + e1;
#pragma unroll
            for (int d = 1; d < 16; d <<= 1) su += __shfl_xor(su, d);
            float is = 1.0f / su;
            float p0 = e0 * is, p1 = e1 * is;
            const int gb = lane & 48;     // 16-lane group base
            int4 iv4 = *(const int4*)(&invs[s2 * V_ + j0 * 4]);
            int ivv[4] = {iv4.x, iv4.y, iv4.z, iv4.w};
            float o[4];
#pragma unroll
            for (int e = 0; e < 4; e++) {
                float ga = __shfl(p0, gb + (ivv[e] & 15));
                float gc = __shfl(p1, gb + (ivv[e] & 15));
                o[e] = (ivv[e] < 0) ? 0.f : ((ivv[e] < 16) ? ga : gc);
            }
            *(float4*)(out + ((size_t)(r0 + r) * T_ + (i - 2)) * V_ + j0 * 4) = *(float4*)o;
        }

        // ---- tanh + fp16 hi/lo split -> x[cur^1] ----
        if (s0 >= 0) {
            float4 bb = *(const float4*)(&b1s[s0 * NL + wave * 16 + q * 4]);
            float bv[4] = {bb.x, bb.y, bb.z, bb.w};
            f16x4 hv, lv;
#pragma unroll
            for (int e = 0; e < 4; e++) {
                float h = fast_tanh(acc1[e] + bv[e]);
                f16 hh = (f16)h;
                hv[e] = hh;
                lv[e] = (f16)(h - (float)hh);
            }
            const int a = xaddr(wave, q, n);
            *(f16x4*)(&xh[cur ^ 1][a]) = hv;
            *(f16x4*)(&xl[cur ^ 1][a]) = lv;
        }

        s2 = s1; s1 = s0; s0 = ns0;
        LGKM_BARRIER();
    }
#undef G1S
}

extern "C" void kernel_launch(void* const* d_in, const int* in_sizes, int n_in,
                              void* d_out, int out_size, void* d_ws, size_t ws_size,
                              hipStream_t stream) {
    const float* latent0   = (const float*)d_in[0];
    const float* W1        = (const float*)d_in[1];
    const float* b1        = (const float*)d_in[2];
    const float* W2        = (const float*)d_in[3];
    const float* b2        = (const float*)d_in[4];
    const int*   state_seq = (const int*)d_in[5];
    const int*   out_idx   = (const int*)d_in[6];
    float* out = (float*)d_out;

    f16*  W1F = (f16*)d_ws;                              // 8 MB
    char* W1Q = (char*)(W1F + (size_t)NS * NL * NL);     // 4 MB
    f16*  W2F = (f16*)(W1Q + (size_t)NS * NL * NL);      // 1 MB
    char* W2Q = (char*)(W2F + (size_t)NS * NO * NL);     // 0.5 MB
    int*  inv = (int*)(W2Q + (size_t)NS * NO * NL);

    const int n4_w1 = NS * NL * NL / 4;   // 1,048,576
    const int n4_w2 = NS * NO * NL / 4;   // 131,072
    split_w_frag<4><<<n4_w1 / 256, 256, 0, stream>>>(W1, W1F, W1Q, n4_w1);
    split_w_frag<1><<<n4_w2 / 256, 256, 0, stream>>>(W2, W2F, W2Q, n4_w2);
    inv_kernel<<<(NS * V_ + 255) / 256, 256, 0, stream>>>(out_idx, inv);

    lalr_main<<<NBLK, 1024, 0, stream>>>(latent0, b1, b2, state_seq, inv,
                                         W1F, W1Q, W2F, W2Q, out);
}

// Round 10
// 549.580 us; speedup vs baseline: 1.0461x; 1.0447x over previous
//
#include <hip/hip_runtime.h>

// Problem dims
#define B_  4096
#define T_  128
#define NL  256
#define NS  64
#define NO  32
#define V_  64
#define RB  16            // rows per block
#define NBLK (B_ / RB)    // 256 blocks

typedef _Float16 f16;
typedef f16   f16x8 __attribute__((ext_vector_type(8)));
typedef f16   f16x4 __attribute__((ext_vector_type(4)));
typedef f16   f16x2 __attribute__((ext_vector_type(2)));
typedef int   ix2   __attribute__((ext_vector_type(2)));
typedef float f32x4 __attribute__((ext_vector_type(4)));

#define MF(a, b, c) __builtin_amdgcn_mfma_f32_16x16x32_f16(a, b, c, 0, 0, 0)

// lgkm-only barrier: block communication is exclusively via LDS.
#define LGKM_BARRIER() asm volatile("s_waitcnt lgkmcnt(0)\n\ts_barrier" ::: "memory")

// Manual loads into the wave's vmcnt FIFO (flat-global, per-lane 64b addr).
#define GLOAD4(dst, ptr) \
    asm volatile("global_load_dwordx4 %0, %1, off" : "=v"(dst) : "v"(ptr))
#define GLOADQ(dst, ptr) \
    asm volatile("global_load_dwordx2 %0, %1, off" : "=v"(dst) : "v"(ptr))

// ---------------------------------------------------------------------------
// Split fp32 weights -> fp16 hi plane + BIASED int8 lo plane (scale 2^-20,
// stored byte = q+128 in [1,255]), both in MFMA A-fragment order:
//   elem idx = (((s*NT + t)*8 + ks)*512) + L*8 + j
//   maps to  W[s][t*16 + (L&15)][ks*32 + (L>>4)*8 + j]
// |w| <= ~0.35 -> fp16 ulp <= 2^-12 -> |lo| <= 2^-13 -> |q| <= ~64.
// Quantization error 2^-21 absolute (better than bf16 hi/lo pair's 2^-18).
// ---------------------------------------------------------------------------
template <int TSHIFT>
__global__ void split_w_frag(const float* __restrict__ src,
                             f16* __restrict__ hi, unsigned char* __restrict__ qlo,
                             int total4) {
    int t4 = blockIdx.x * blockDim.x + threadIdx.x;
    if (t4 >= total4) return;
    const int jb   = (t4 & 1) * 4;
    const int L    = (t4 >> 1) & 63;
    const int ks   = (t4 >> 7) & 7;
    const int rest = t4 >> 10;
    const int t    = rest & ((1 << TSHIFT) - 1);
    const int s    = rest >> TSHIFT;
    const int row  = ((s << TSHIFT) + t) * 16 + (L & 15);
    const int k    = ks * 32 + (L >> 4) * 8 + jb;
    const float4 v = *(const float4*)(src + (size_t)row * NL + k);
    float vv[4] = {v.x, v.y, v.z, v.w};
    f16x4 h;
    unsigned qb = 0;
#pragma unroll
    for (int e = 0; e < 4; e++) {
        f16 hh = (f16)vv[e];
        h[e] = hh;
        float lo = vv[e] - (float)hh;
        float qf = fminf(fmaxf(rintf(lo * 0x1p20f), -127.f), 127.f);
        qb |= (unsigned)(((int)qf + 128) & 0xff) << (8 * e);
    }
    *(f16x4*)(hi + (size_t)t4 * 4) = h;
    ((unsigned*)qlo)[t4] = qb;
}

// inv[s][v] = last j with out_idx[s][j]==v, else -1 (numpy last-dup-wins)
__global__ void inv_kernel(const int* __restrict__ out_idx, int* __restrict__ inv) {
    int t = blockIdx.x * blockDim.x + threadIdx.x;
    if (t >= NS * V_) return;
    int s = t >> 6, v = t & 63;
    int jf = -1;
#pragma unroll
    for (int j = 0; j < NO; j++)
        if (out_idx[(s << 5) | j] == v) jf = j;
    inv[t] = jf;
}

__device__ __forceinline__ float fast_tanh(float z) {
    float e = __expf(2.0f * z);
    return 1.0f - 2.0f / (e + 1.0f);
}

// Biased-byte lo fragment -> fp16x8, EXACT, 8 ops:
// v_perm builds packed fp16 (0x3C00|byte) = 1 + u*2^-10 (u = q+128), then one
// packed FMA: (v)*2^-10 - 1.125*2^-10 = (u-128)*2^-20 = q*2^-20.
// Operands are 2^-20-granular -> no rounding; subnormal results exact
// (f16 denorm mode is IEEE on amdgcn; round-9 fed identical subnormals
// through MFMA successfully).
__device__ __forceinline__ f16x8 unpack_q(ix2 qd) {
    const unsigned C = 0x3C3C3C3Cu;
    unsigned d01 = __builtin_amdgcn_perm(C, (unsigned)qd[0], 0x05010400u);
    unsigned d23 = __builtin_amdgcn_perm(C, (unsigned)qd[0], 0x05030402u);
    unsigned d45 = __builtin_amdgcn_perm(C, (unsigned)qd[1], 0x05010400u);
    unsigned d67 = __builtin_amdgcn_perm(C, (unsigned)qd[1], 0x05030402u);
    const f16 k1 = (f16)0x1p-10f;
    const f16 k2 = (f16)(-0x1.2p-10f);      // -1.125 * 2^-10
    f16x2 kk1 = {k1, k1}, kk2 = {k2, k2};
    union { unsigned u; f16x2 h; } a, b, c, d;
    a.u = d01; b.u = d23; c.u = d45; d.u = d67;
    f16x2 r0 = a.h * kk1 + kk2;
    f16x2 r1 = b.h * kk1 + kk2;
    f16x2 r2 = c.h * kk1 + kk2;
    f16x2 r3 = d.h * kk1 + kk2;
    f16x8 r;
    r[0] = r0[0]; r[1] = r0[1]; r[2] = r1[0]; r[3] = r1[1];
    r[4] = r2[0]; r[5] = r2[1]; r[6] = r3[0]; r[7] = r3[1];
    return r;
}

// x fragment-order address for element (batch row n, k = t*16 + q*4):
__device__ __forceinline__ int xaddr(int t, int q, int n) {
    return ((t >> 1) * 512) + (((t & 1) * 2 + (q >> 1)) * 128) + n * 8 + (q & 1) * 4;
}

// ---------------------------------------------------------------------------
// Persistent per-block recurrence, 256 blocks x 16 waves, 1 block/CU.
// Weight stream is 3 B/weight (fp16 hi dwordx4 + int8 lo dwordx2): per-CU
// 216 KB/step vs 288 KB for the bf16 hi/lo pair -- attacks the measured
// per-CU delivery cap (~35 B/cy, invariant across rounds 0-8).
// FIFO/step/wave = 8x(W1 hi,lo) + (W2 hi,lo) = 18 ops (+<=1 out store).
// At slice-ks wait: younger = 2(7-ks) + 2 + 2ks = 16 -> vmcnt(16) uniform;
// GEMM2 wait: younger = 16 W1 reissues -> vmcnt(16); tails vmcnt(0).
// Waits TIE the consumed regs ("+v") so the VALU unpack cannot be hoisted
// above the wait (rule-18: "memory" doesn't order register-only ops).
// Rotation (blockIdx>>3)&7 de-syncs same-XCD streams (+1.6%, round 6).
// Round 10: unpack_q is the 8-op perm+pk_fma version (round-9's ~36-op
// cvt chain pushed VALUBusy to 68% and ate the delivery savings).
// ---------------------------------------------------------------------------
__launch_bounds__(1024, 4)
__global__ void lalr_main(const float* __restrict__ latent0,
                          const float* __restrict__ b1,
                          const float* __restrict__ b2,
                          const int*   __restrict__ state_seq,
                          const int*   __restrict__ inv,
                          const f16*   __restrict__ W1F,
                          const unsigned char* __restrict__ W1Q,
                          const f16*   __restrict__ W2F,
                          const unsigned char* __restrict__ W2Q,
                          float* __restrict__ out) {
    __shared__ f16   xh[2][4096];        // 16 KB  (frag order, double buffered)
    __shared__ f16   xl[2][4096];        // 16 KB
    __shared__ float Sp[2][8][16][36];   // 36 KB  GEMM2 K-partials (pad 36)
    __shared__ float b1s[NS * NL];       // 64 KB
    __shared__ float b2s[NS * NO];       //  8 KB
    __shared__ int   invs[NS * V_];      // 16 KB
    __shared__ int   sseq[T_];           // 0.5 KB   total 160,256 B

    const int tid  = threadIdx.x;
    const int wave = tid >> 6;           // 0..15
    const int lane = tid & 63;
    const int n    = lane & 15;          // batch row
    const int q    = lane >> 4;          // quad
    const int r0   = blockIdx.x * RB;
    const int t2   = wave & 1;           // GEMM2 col-tile
    const int ks2  = wave >> 1;          // GEMM2 K-slice

    // Rotated GEMM1 slice visit order (block-uniform).
    const int rot = (blockIdx.x >> 3) & 7;
    const int rs0 = (0 + rot) & 7, rs1 = (1 + rot) & 7, rs2 = (2 + rot) & 7,
              rs3 = (3 + rot) & 7, rs4 = (4 + rot) & 7, rs5 = (5 + rot) & 7,
              rs6 = (6 + rot) & 7, rs7 = (7 + rot) & 7;

    // ---- stage uniforms into LDS (prologue-only plain global traffic) ----
    for (int k = tid; k < NS * NL / 4; k += 1024)
        ((float4*)b1s)[k] = ((const float4*)b1)[k];
    if (tid < NS * NO / 4) ((float4*)b2s)[tid] = ((const float4*)b2)[tid];
    if (tid < NS * V_ / 4) ((int4*)invs)[tid] = ((const int4*)inv)[tid];
    if (tid < T_) sseq[tid] = state_seq[tid];

    // ---- init: latent0 -> x[0] fp16 hi/lo fragments ----
    {
        float4 v = *(const float4*)(latent0 + (size_t)(r0 + n) * NL + wave * 16 + q * 4);
        float vv[4] = {v.x, v.y, v.z, v.w};
        f16x4 hv, lv;
#pragma unroll
        for (int e = 0; e < 4; e++) {
            f16 hh = (f16)vv[e];
            hv[e] = hh;
            lv[e] = (f16)(vv[e] - (float)hh);
        }
        const int a = xaddr(wave, q, n);
        *(f16x4*)(&xh[0][a]) = hv;
        *(f16x4*)(&xl[0][a]) = lv;
    }

    int s0 = state_seq[0], s1 = -1, s2 = -1;

    // FIFO destination registers: 8x (f16x8 hi + ix2 lo) + W2 pair.
    f16x8 pwh0, pwh1, pwh2, pwh3, pwh4, pwh5, pwh6, pwh7;
    ix2   pwq0, pwq1, pwq2, pwq3, pwq4, pwq5, pwq6, pwq7;
    f16x8 w2h2;
    ix2   w2q2;

    const int wfrag = wave * 4096 + lane * 8;   // elem (hi) == byte (lo) offset

    // Prologue: issue L_0 in exact (rotated) consumption order, 18 ops.
    {
        const f16*           h0 = W1F + (size_t)s0 * 65536 + wfrag;
        const unsigned char* q0 = W1Q + (size_t)s0 * 65536 + wfrag;
        GLOAD4(pwh0, h0 + rs0 * 512); GLOADQ(pwq0, q0 + rs0 * 512);
        GLOAD4(pwh1, h0 + rs1 * 512); GLOADQ(pwq1, q0 + rs1 * 512);
        GLOAD4(pwh2, h0 + rs2 * 512); GLOADQ(pwq2, q0 + rs2 * 512);
        GLOAD4(pwh3, h0 + rs3 * 512); GLOADQ(pwq3, q0 + rs3 * 512);
        GLOAD4(pwh4, h0 + rs4 * 512); GLOADQ(pwq4, q0 + rs4 * 512);
        GLOAD4(pwh5, h0 + rs5 * 512); GLOADQ(pwq5, q0 + rs5 * 512);
        GLOAD4(pwh6, h0 + rs6 * 512); GLOADQ(pwq6, q0 + rs6 * 512);
        GLOAD4(pwh7, h0 + rs7 * 512); GLOADQ(pwq7, q0 + rs7 * 512);
        const f16*           c2h = W2F + (size_t)((s0 * 2 + t2) * 8 + ks2) * 512 + lane * 8;
        const unsigned char* c2q = W2Q + (size_t)((s0 * 2 + t2) * 8 + ks2) * 512 + lane * 8;
        GLOAD4(w2h2, c2h); GLOADQ(w2q2, c2q);   // placeholder (iter-0 GEMM2 skipped)
    }

    LGKM_BARRIER();      // x[0]/staging visible; weight loads stay in flight

// One GEMM1 slice (rotated physical slice rs): LDS x reads, tied counted
// wait, fence, 8-op unpack + 3 MFMA, reissue hi/lo pair for next step.
#define G1S(ks, rs) {                                                       \
        const int xo = (rs) * 512 + lane * 8;                               \
        f16x8 xa = *(const f16x8*)(&xh[cur][xo]);                           \
        f16x8 xb = *(const f16x8*)(&xl[cur][xo]);                           \
        asm volatile("s_waitcnt vmcnt(16)"                                  \
                     : "+v"(pwh##ks), "+v"(pwq##ks) :: "memory");           \
        __builtin_amdgcn_sched_barrier(0);                                  \
        acc1 = MF(pwh##ks, xa, acc1);                                       \
        f16x8 wl = unpack_q(pwq##ks);                                       \
        acc1 = MF(wl, xa, acc1);                                            \
        acc1 = MF(pwh##ks, xb, acc1);                                       \
        GLOAD4(pwh##ks, nh0 + (rs) * 512);                                  \
        GLOADQ(pwq##ks, nq0 + (rs) * 512);                                  \
    }

    for (int i = 0; i <= T_ + 1; i++) {
        const int ib  = i & 1;
        const int cur = ib;

        // next-step W1 base pointers (dummy state 0 in tail keeps FIFO shape)
        const int ns0 = (i + 1 < T_) ? sseq[i + 1] : -1;
        const int ls  = (ns0 >= 0) ? ns0 : 0;
        const f16*           nh0 = W1F + (size_t)ls * 65536 + wfrag;
        const unsigned char* nq0 = W1Q + (size_t)ls * 65536 + wfrag;

        // ---- GEMM1 (state s0): full K=256, vmcnt-paced, rotated slices ----
        f32x4 acc1;
        if (s0 >= 0) {
            acc1 = (f32x4){0.f, 0.f, 0.f, 0.f};
            G1S(0, rs0)
            G1S(1, rs1)
            G1S(2, rs2)
            G1S(3, rs3)
            G1S(4, rs4)
            G1S(5, rs5)
            G1S(6, rs6)
            G1S(7, rs7)
        }

        // ---- GEMM2 (state s1): task (t2, ks2) ----
        if (s1 >= 0) {
            const int xo2 = ks2 * 512 + lane * 8;
            f16x8 xa = *(const f16x8*)(&xh[cur][xo2]);
            f16x8 xb = *(const f16x8*)(&xl[cur][xo2]);
            if (s0 >= 0) {
                asm volatile("s_waitcnt vmcnt(16)"
                             : "+v"(w2h2), "+v"(w2q2) :: "memory");
            } else {
                // tail: GEMM1 skipped -> no W1 reissues ahead; drain
                asm volatile("s_waitcnt vmcnt(0)"
                             : "+v"(w2h2), "+v"(w2q2) :: "memory");
            }
            __builtin_amdgcn_sched_barrier(0);
            f32x4 a2 = (f32x4){0.f, 0.f, 0.f, 0.f};
            a2 = MF(w2h2, xa, a2);
            f16x8 wl2 = unpack_q(w2q2);
            a2 = MF(wl2, xa, a2);
            a2 = MF(w2h2, xb, a2);
            if (ks2 == 0) {
                float4 bb = *(const float4*)(&b2s[s1 * NO + t2 * 16 + q * 4]);
                a2[0] += bb.x; a2[1] += bb.y; a2[2] += bb.z; a2[3] += bb.w;
            }
            *(f32x4*)(&Sp[ib][ks2][n][t2 * 16 + q * 4]) = a2;
        }
        if (s0 >= 0) {   // reissue W2 pair for next iteration (state = current s0)
            const f16*           n2h = W2F + (size_t)((s0 * 2 + t2) * 8 + ks2) * 512 + lane * 8;
            const unsigned char* n2q = W2Q + (size_t)((s0 * 2 + t2) * 8 + ks2) * 512 + lane * 8;
            GLOAD4(w2h2, n2h);
            GLOADQ(w2q2, n2q);
        }

        // ---- softmax + shfl-scatter + store for step i-2 (first 4 waves) ----
        if (s2 >= 0 && tid < 256) {
            const int r  = tid >> 4;
            const int j0 = tid & 15;
            const int pb = (i - 1) & 1;
            float v0 = 0.f, v1 = 0.f;
#pragma unroll
            for (int w = 0; w < 8; w++) {
                v0 += Sp[pb][w][r][j0];
                v1 += Sp[pb][w][r][j0 + 16];
            }
            float m = fmaxf(v0, v1);
#pragma unroll
            for (int d = 1; d < 16; d <<= 1) m = fmaxf(m, __shfl_xor(m, d));
            float e0 = __expf(v0 - m), e1 = __expf(v1 - m);
            float su = e0 + e1;
#pragma unroll
            for (int d = 1; d < 16; d <<= 1) su += __shfl_xor(su, d);
            float is = 1.0f / su;
            float p0 = e0 * is, p1 = e1 * is;
            const int gb = lane & 48;     // 16-lane group base
            int4 iv4 = *(const int4*)(&invs[s2 * V_ + j0 * 4]);
            int ivv[4] = {iv4.x, iv4.y, iv4.z, iv4.w};
            float o[4];
#pragma unroll
            for (int e = 0; e < 4; e++) {
                float ga = __shfl(p0, gb + (ivv[e] & 15));
                float gc = __shfl(p1, gb + (ivv[e] & 15));
                o[e] = (ivv[e] < 0) ? 0.f : ((ivv[e] < 16) ? ga : gc);
            }
            *(float4*)(out + ((size_t)(r0 + r) * T_ + (i - 2)) * V_ + j0 * 4) = *(float4*)o;
        }

        // ---- tanh + fp16 hi/lo split -> x[cur^1] ----
        if (s0 >= 0) {
            float4 bb = *(const float4*)(&b1s[s0 * NL + wave * 16 + q * 4]);
            float bv[4] = {bb.x, bb.y, bb.z, bb.w};
            f16x4 hv, lv;
#pragma unroll
            for (int e = 0; e < 4; e++) {
                float h = fast_tanh(acc1[e] + bv[e]);
                f16 hh = (f16)h;
                hv[e] = hh;
                lv[e] = (f16)(h - (float)hh);
            }
            const int a = xaddr(wave, q, n);
            *(f16x4*)(&xh[cur ^ 1][a]) = hv;
            *(f16x4*)(&xl[cur ^ 1][a]) = lv;
        }

        s2 = s1; s1 = s0; s0 = ns0;
        LGKM_BARRIER();
    }
#undef G1S
}

extern "C" void kernel_launch(void* const* d_in, const int* in_sizes, int n_in,
                              void* d_out, int out_size, void* d_ws, size_t ws_size,
                              hipStream_t stream) {
    const float* latent0   = (const float*)d_in[0];
    const float* W1        = (const float*)d_in[1];
    const float* b1        = (const float*)d_in[2];
    const float* W2        = (const float*)d_in[3];
    const float* b2        = (const float*)d_in[4];
    const int*   state_seq = (const int*)d_in[5];
    const int*   out_idx   = (const int*)d_in[6];
    float* out = (float*)d_out;

    f16*           W1F = (f16*)d_ws;                               // 8 MB
    unsigned char* W1Q = (unsigned char*)(W1F + (size_t)NS * NL * NL);  // 4 MB
    f16*           W2F = (f16*)(W1Q + (size_t)NS * NL * NL);       // 1 MB
    unsigned char* W2Q = (unsigned char*)(W2F + (size_t)NS * NO * NL);  // 0.5 MB
    int*           inv = (int*)(W2Q + (size_t)NS * NO * NL);

    const int n4_w1 = NS * NL * NL / 4;   // 1,048,576
    const int n4_w2 = NS * NO * NL / 4;   // 131,072
    split_w_frag<4><<<n4_w1 / 256, 256, 0, stream>>>(W1, W1F, W1Q, n4_w1);
    split_w_frag<1><<<n4_w2 / 256, 256, 0, stream>>>(W2, W2F, W2Q, n4_w2);
    inv_kernel<<<(NS * V_ + 255) / 256, 256, 0, stream>>>(out_idx, inv);

    lalr_main<<<NBLK, 1024, 0, stream>>>(latent0, b1, b2, state_seq, inv,
                                         W1F, W1Q, W2F, W2Q, out);
}

// Round 11
// 524.059 us; speedup vs baseline: 1.0970x; 1.0487x over previous
//
#include <hip/hip_runtime.h>

// Problem dims
#define B_  4096
#define T_  128
#define NL  256
#define NS  64
#define NO  32
#define V_  64
#define RB  16            // rows per block
#define NBLK (B_ / RB)    // 256 blocks

typedef _Float16 f16;
typedef f16   f16x8 __attribute__((ext_vector_type(8)));
typedef f16   f16x4 __attribute__((ext_vector_type(4)));
typedef f16   f16x2 __attribute__((ext_vector_type(2)));
typedef int   ix2   __attribute__((ext_vector_type(2)));
typedef int   ix4   __attribute__((ext_vector_type(4)));
typedef float f32x4 __attribute__((ext_vector_type(4)));

#define MF(a, b, c) __builtin_amdgcn_mfma_f32_16x16x32_f16(a, b, c, 0, 0, 0)

// lgkm-only barrier: block communication is exclusively via LDS.
#define LGKM_BARRIER() asm volatile("s_waitcnt lgkmcnt(0)\n\ts_barrier" ::: "memory")

// Manual loads into the wave's vmcnt FIFO (flat-global, per-lane 64b addr).
#define GLOAD4(dst, ptr) \
    asm volatile("global_load_dwordx4 %0, %1, off" : "=v"(dst) : "v"(ptr))
#define GLOADQ(dst, ptr) \
    asm volatile("global_load_dwordx2 %0, %1, off" : "=v"(dst) : "v"(ptr))

// ---------------------------------------------------------------------------
// Split fp32 weights -> fp16 hi plane + BIASED int8 lo plane (scale 2^-20,
// stored byte = q+128), hi in MFMA A-fragment order:
//   elem idx = (((s*NT + t)*8 + ks)*512) + L*8 + j
// Lo layout differs by PACK:
//   PACK=0 (W2): byte idx = elem idx (dwordx2 loads, 8B/lane)
//   PACK=1 (W1): slice-PAIR packed so one dwordx4 carries two slices' lo:
//     byte = (s*16+t)*4096 + (ks>>1)*1024 + L*16 + (ks&1)*8 + j
//   -> lane L reads 16B = [slice 2p lo (8B) | slice 2p+1 lo (8B)].
// |w| <= ~0.35 -> fp16 ulp <= 2^-12 -> |lo| <= 2^-13 -> |q| <= ~64.
// ---------------------------------------------------------------------------
template <int TSHIFT, int PACK>
__global__ void split_w_frag(const float* __restrict__ src,
                             f16* __restrict__ hi, unsigned char* __restrict__ qlo,
                             int total4) {
    int t4 = blockIdx.x * blockDim.x + threadIdx.x;
    if (t4 >= total4) return;
    const int jb   = (t4 & 1) * 4;
    const int L    = (t4 >> 1) & 63;
    const int ks   = (t4 >> 7) & 7;
    const int rest = t4 >> 10;
    const int t    = rest & ((1 << TSHIFT) - 1);
    const int s    = rest >> TSHIFT;
    const int row  = ((s << TSHIFT) + t) * 16 + (L & 15);
    const int k    = ks * 32 + (L >> 4) * 8 + jb;
    const float4 v = *(const float4*)(src + (size_t)row * NL + k);
    float vv[4] = {v.x, v.y, v.z, v.w};
    f16x4 h;
    unsigned qb = 0;
#pragma unroll
    for (int e = 0; e < 4; e++) {
        f16 hh = (f16)vv[e];
        h[e] = hh;
        float lo = vv[e] - (float)hh;
        float qf = fminf(fmaxf(rintf(lo * 0x1p20f), -127.f), 127.f);
        qb |= (unsigned)(((int)qf + 128) & 0xff) << (8 * e);
    }
    *(f16x4*)(hi + (size_t)t4 * 4) = h;
    if (PACK) {
        const int dw = (((s << TSHIFT) + t) * 4 + (ks >> 1)) * 256
                       + L * 4 + (ks & 1) * 2 + (jb >> 2);
        ((unsigned*)qlo)[dw] = qb;
    } else {
        ((unsigned*)qlo)[t4] = qb;
    }
}

// inv[s][v] = last j with out_idx[s][j]==v, else -1 (numpy last-dup-wins)
__global__ void inv_kernel(const int* __restrict__ out_idx, int* __restrict__ inv) {
    int t = blockIdx.x * blockDim.x + threadIdx.x;
    if (t >= NS * V_) return;
    int s = t >> 6, v = t & 63;
    int jf = -1;
#pragma unroll
    for (int j = 0; j < NO; j++)
        if (out_idx[(s << 5) | j] == v) jf = j;
    inv[t] = jf;
}

__device__ __forceinline__ float fast_tanh(float z) {
    float e = __expf(2.0f * z);
    return 1.0f - 2.0f / (e + 1.0f);
}

// Biased bytes (2 dwords = 8 weights) -> fp16x8, EXACT, 8 ops:
// perm builds packed (0x3C00|byte) = 1 + u*2^-10; pk_fma * 2^-10 - 1.125*2^-10
// = (u-128)*2^-20 = q*2^-20.
__device__ __forceinline__ f16x8 unpack_q2(unsigned q0, unsigned q1) {
    const unsigned C = 0x3C3C3C3Cu;
    unsigned d01 = __builtin_amdgcn_perm(C, q0, 0x05010400u);
    unsigned d23 = __builtin_amdgcn_perm(C, q0, 0x05030402u);
    unsigned d45 = __builtin_amdgcn_perm(C, q1, 0x05010400u);
    unsigned d67 = __builtin_amdgcn_perm(C, q1, 0x05030402u);
    const f16 k1 = (f16)0x1p-10f;
    const f16 k2 = (f16)(-0x1.2p-10f);      // -1.125 * 2^-10
    f16x2 kk1 = {k1, k1}, kk2 = {k2, k2};
    union { unsigned u; f16x2 h; } a, b, c, d;
    a.u = d01; b.u = d23; c.u = d45; d.u = d67;
    f16x2 r0 = a.h * kk1 + kk2;
    f16x2 r1 = b.h * kk1 + kk2;
    f16x2 r2 = c.h * kk1 + kk2;
    f16x2 r3 = d.h * kk1 + kk2;
    f16x8 r;
    r[0] = r0[0]; r[1] = r0[1]; r[2] = r1[0]; r[3] = r1[1];
    r[4] = r2[0]; r[5] = r2[1]; r[6] = r3[0]; r[7] = r3[1];
    return r;
}

// x fragment-order address for element (batch row n, k = t*16 + q*4):
__device__ __forceinline__ int xaddr(int t, int q, int n) {
    return ((t >> 1) * 512) + (((t & 1) * 2 + (q >> 1)) * 128) + n * 8 + (q & 1) * 4;
}

// ---------------------------------------------------------------------------
// Persistent per-block recurrence, 256 blocks x 16 waves, 1 block/CU.
// REQUEST-PACKED weight stream: the series r6/r8/r9/r10 pinned at ~29 cy per
// wave-request/CU regardless of bytes (18 req -> 8.3k cy; 21 -> 8.9k) =>
// requests, not bytes, are the vmem currency. This round: 14 requests/step
// (8 W1-hi x4 + 4 W1-lo-PAIR x4 + W2 hi x4 + W2 lo x2), bytes = r10.
// Stream/step: [h0,h1,q01, h2,h3,q23, h4,h5,q45, h6,h7,q67, w2h,w2q,(st)].
// In-order retirement => ONE wait per slice-pair: at pair-p wait (target
// q-pair issued prev step), younger = 3(3-p) + 2 + 3p = 11 invariant ->
// vmcnt(11). GEMM2: target w2 pair, younger = 12 step-i W1 ops -> vmcnt(12).
// Tails drain vmcnt(0). Waits tie consumed regs ("+v") per rule-18.
// Rotation restricted to EVEN shifts (pairs stay physical): prot 0..3.
// ---------------------------------------------------------------------------
__launch_bounds__(1024, 4)
__global__ void lalr_main(const float* __restrict__ latent0,
                          const float* __restrict__ b1,
                          const float* __restrict__ b2,
                          const int*   __restrict__ state_seq,
                          const int*   __restrict__ inv,
                          const f16*   __restrict__ W1F,
                          const unsigned char* __restrict__ W1Q,
                          const f16*   __restrict__ W2F,
                          const unsigned char* __restrict__ W2Q,
                          float* __restrict__ out) {
    __shared__ f16   xh[2][4096];        // 16 KB  (frag order, double buffered)
    __shared__ f16   xl[2][4096];        // 16 KB
    __shared__ float Sp[2][8][16][36];   // 36 KB  GEMM2 K-partials (pad 36)
    __shared__ float b1s[NS * NL];       // 64 KB
    __shared__ float b2s[NS * NO];       //  8 KB
    __shared__ int   invs[NS * V_];      // 16 KB
    __shared__ int   sseq[T_];           // 0.5 KB   total 160,256 B

    const int tid  = threadIdx.x;
    const int wave = tid >> 6;           // 0..15
    const int lane = tid & 63;
    const int n    = lane & 15;          // batch row
    const int q    = lane >> 4;          // quad
    const int r0   = blockIdx.x * RB;
    const int t2   = wave & 1;           // GEMM2 col-tile
    const int ks2  = wave >> 1;          // GEMM2 K-slice

    // Even rotation over slice PAIRS (block-uniform): pair slot p holds
    // physical pair (p+prot)&3; rp = phys-pair * 1024 serves x-elems,
    // hi-elems AND lo-bytes (all 1024-granular).
    const int prot = (blockIdx.x >> 3) & 3;
    const int rp0 = ((0 + prot) & 3) * 1024;
    const int rp1 = ((1 + prot) & 3) * 1024;
    const int rp2 = ((2 + prot) & 3) * 1024;
    const int rp3 = ((3 + prot) & 3) * 1024;

    // ---- stage uniforms into LDS (prologue-only plain global traffic) ----
    for (int k = tid; k < NS * NL / 4; k += 1024)
        ((float4*)b1s)[k] = ((const float4*)b1)[k];
    if (tid < NS * NO / 4) ((float4*)b2s)[tid] = ((const float4*)b2)[tid];
    if (tid < NS * V_ / 4) ((int4*)invs)[tid] = ((const int4*)inv)[tid];
    if (tid < T_) sseq[tid] = state_seq[tid];

    // ---- init: latent0 -> x[0] fp16 hi/lo fragments ----
    {
        float4 v = *(const float4*)(latent0 + (size_t)(r0 + n) * NL + wave * 16 + q * 4);
        float vv[4] = {v.x, v.y, v.z, v.w};
        f16x4 hv, lv;
#pragma unroll
        for (int e = 0; e < 4; e++) {
            f16 hh = (f16)vv[e];
            hv[e] = hh;
            lv[e] = (f16)(vv[e] - (float)hh);
        }
        const int a = xaddr(wave, q, n);
        *(f16x4*)(&xh[0][a]) = hv;
        *(f16x4*)(&xl[0][a]) = lv;
    }

    int s0 = state_seq[0], s1 = -1, s2 = -1;

    // FIFO destination registers: 8 hi f16x8 + 4 packed-lo ix4 + W2 pair.
    f16x8 pwhE0, pwhE1, pwhE2, pwhE3;    // even slice of each pair slot
    f16x8 pwhO0, pwhO1, pwhO2, pwhO3;    // odd slice
    ix4   pq0, pq1, pq2, pq3;            // packed lo pair
    f16x8 w2h2;
    ix2   w2q2;

    const int wfragH = wave * 4096 + lane * 8;    // hi elem offset per wave
    const int wfragQ = wave * 4096 + lane * 16;   // packed lo byte offset

    // Prologue: issue L_0 in exact consumption order (14 ops).
    {
        const f16*           h0 = W1F + (size_t)s0 * 65536 + wfragH;
        const unsigned char* q0 = W1Q + (size_t)s0 * 65536 + wfragQ;
        GLOAD4(pwhE0, h0 + rp0); GLOAD4(pwhO0, h0 + rp0 + 512); GLOAD4(pq0, q0 + rp0);
        GLOAD4(pwhE1, h0 + rp1); GLOAD4(pwhO1, h0 + rp1 + 512); GLOAD4(pq1, q0 + rp1);
        GLOAD4(pwhE2, h0 + rp2); GLOAD4(pwhO2, h0 + rp2 + 512); GLOAD4(pq2, q0 + rp2);
        GLOAD4(pwhE3, h0 + rp3); GLOAD4(pwhO3, h0 + rp3 + 512); GLOAD4(pq3, q0 + rp3);
        const f16*           c2h = W2F + (size_t)((s0 * 2 + t2) * 8 + ks2) * 512 + lane * 8;
        const unsigned char* c2q = W2Q + (size_t)((s0 * 2 + t2) * 8 + ks2) * 512 + lane * 8;
        GLOAD4(w2h2, c2h); GLOADQ(w2q2, c2q);   // placeholder (iter-0 GEMM2 skipped)
    }

    LGKM_BARRIER();      // x[0]/staging visible; weight loads stay in flight

// One slice-PAIR (physical pair offset rp): 4+4 LDS x reads, one tied
// vmcnt(11) wait covering hi-even/hi-odd/lo-pair (in-order retirement),
// 6 MFMA + 2 unpacks, reissue 3 requests in stream order hE, hO, q.
#define G1P(p, rp) {                                                        \
        f16x8 xa0 = *(const f16x8*)(&xh[cur][(rp) + lane * 8]);             \
        f16x8 xb0 = *(const f16x8*)(&xl[cur][(rp) + lane * 8]);             \
        f16x8 xa1 = *(const f16x8*)(&xh[cur][(rp) + 512 + lane * 8]);       \
        f16x8 xb1 = *(const f16x8*)(&xl[cur][(rp) + 512 + lane * 8]);       \
        asm volatile("s_waitcnt vmcnt(11)"                                  \
                     : "+v"(pwhE##p), "+v"(pwhO##p), "+v"(pq##p)            \
                     :: "memory");                                          \
        __builtin_amdgcn_sched_barrier(0);                                  \
        acc1 = MF(pwhE##p, xa0, acc1);                                      \
        f16x8 wle = unpack_q2((unsigned)pq##p[0], (unsigned)pq##p[1]);      \
        acc1 = MF(wle, xa0, acc1);                                          \
        acc1 = MF(pwhE##p, xb0, acc1);                                      \
        GLOAD4(pwhE##p, nh0 + (rp));                                        \
        acc1 = MF(pwhO##p, xa1, acc1);                                      \
        f16x8 wlo = unpack_q2((unsigned)pq##p[2], (unsigned)pq##p[3]);      \
        acc1 = MF(wlo, xa1, acc1);                                          \
        acc1 = MF(pwhO##p, xb1, acc1);                                      \
        GLOAD4(pwhO##p, nh0 + (rp) + 512);                                  \
        GLOAD4(pq##p, nq0 + (rp));                                          \
    }

    for (int i = 0; i <= T_ + 1; i++) {
        const int ib  = i & 1;
        const int cur = ib;

        // next-step W1 base pointers (dummy state 0 in tail keeps FIFO shape)
        const int ns0 = (i + 1 < T_) ? sseq[i + 1] : -1;
        const int ls  = (ns0 >= 0) ? ns0 : 0;
        const f16*           nh0 = W1F + (size_t)ls * 65536 + wfragH;
        const unsigned char* nq0 = W1Q + (size_t)ls * 65536 + wfragQ;

        // ---- GEMM1 (state s0): full K=256, pair-paced, rotated pairs ----
        f32x4 acc1;
        if (s0 >= 0) {
            acc1 = (f32x4){0.f, 0.f, 0.f, 0.f};
            G1P(0, rp0)
            G1P(1, rp1)
            G1P(2, rp2)
            G1P(3, rp3)
        }

        // ---- GEMM2 (state s1): task (t2, ks2) ----
        if (s1 >= 0) {
            const int xo2 = ks2 * 512 + lane * 8;
            f16x8 xa = *(const f16x8*)(&xh[cur][xo2]);
            f16x8 xb = *(const f16x8*)(&xl[cur][xo2]);
            if (s0 >= 0) {
                asm volatile("s_waitcnt vmcnt(12)"
                             : "+v"(w2h2), "+v"(w2q2) :: "memory");
            } else {
                // tail: GEMM1 skipped -> drain
                asm volatile("s_waitcnt vmcnt(0)"
                             : "+v"(w2h2), "+v"(w2q2) :: "memory");
            }
            __builtin_amdgcn_sched_barrier(0);
            f32x4 a2 = (f32x4){0.f, 0.f, 0.f, 0.f};
            a2 = MF(w2h2, xa, a2);
            f16x8 wl2 = unpack_q2((unsigned)w2q2[0], (unsigned)w2q2[1]);
            a2 = MF(wl2, xa, a2);
            a2 = MF(w2h2, xb, a2);
            if (ks2 == 0) {
                float4 bb = *(const float4*)(&b2s[s1 * NO + t2 * 16 + q * 4]);
                a2[0] += bb.x; a2[1] += bb.y; a2[2] += bb.z; a2[3] += bb.w;
            }
            *(f32x4*)(&Sp[ib][ks2][n][t2 * 16 + q * 4]) = a2;
        }
        if (s0 >= 0) {   // reissue W2 pair for next iteration (state = current s0)
            const f16*           n2h = W2F + (size_t)((s0 * 2 + t2) * 8 + ks2) * 512 + lane * 8;
            const unsigned char* n2q = W2Q + (size_t)((s0 * 2 + t2) * 8 + ks2) * 512 + lane * 8;
            GLOAD4(w2h2, n2h);
            GLOADQ(w2q2, n2q);
        }

        // ---- softmax + shfl-scatter + store for step i-2 (first 4 waves) ----
        if (s2 >= 0 && tid < 256) {
            const int r  = tid >> 4;
            const int j0 = tid & 15;
            const int pb = (i - 1) & 1;
            float v0 = 0.f, v1 = 0.f;
#pragma unroll
            for (int w = 0; w < 8; w++) {
                v0 += Sp[pb][w][r][j0];
                v1 += Sp[pb][w][r][j0 + 16];
            }
            float m = fmaxf(v0, v1);
#pragma unroll
            for (int d = 1; d < 16; d <<= 1) m = fmaxf(m, __shfl_xor(m, d));
            float e0 = __expf(v0 - m), e1 = __expf(v1 - m);
            float su = e0 + e1;
#pragma unroll
            for (int d = 1; d < 16; d <<= 1) su += __shfl_xor(su, d);
            float is = 1.0f / su;
            float p0 = e0 * is, p1 = e1 * is;
            const int gb = lane & 48;     // 16-lane group base
            int4 iv4 = *(const int4*)(&invs[s2 * V_ + j0 * 4]);
            int ivv[4] = {iv4.x, iv4.y, iv4.z, iv4.w};
            float o[4];
#pragma unroll
            for (int e = 0; e < 4; e++) {
                float ga = __shfl(p0, gb + (ivv[e] & 15));
                float gc = __shfl(p1, gb + (ivv[e] & 15));
                o[e] = (ivv[e] < 0) ? 0.f : ((ivv[e] < 16) ? ga : gc);
            }
            *(float4*)(out + ((size_t)(r0 + r) * T_ + (i - 2)) * V_ + j0 * 4) = *(float4*)o;
        }

        // ---- tanh + fp16 hi/lo split -> x[cur^1] ----
        if (s0 >= 0) {
            float4 bb = *(const float4*)(&b1s[s0 * NL + wave * 16 + q * 4]);
            float bv[4] = {bb.x, bb.y, bb.z, bb.w};
            f16x4 hv, lv;
#pragma unroll
            for (int e = 0; e < 4; e++) {
                float h = fast_tanh(acc1[e] + bv[e]);
                f16 hh = (f16)h;
                hv[e] = hh;
                lv[e] = (f16)(h - (float)hh);
            }
            const int a = xaddr(wave, q, n);
            *(f16x4*)(&xh[cur ^ 1][a]) = hv;
            *(f16x4*)(&xl[cur ^ 1][a]) = lv;
        }

        s2 = s1; s1 = s0; s0 = ns0;
        LGKM_BARRIER();
    }
#undef G1P
}

extern "C" void kernel_launch(void* const* d_in, const int* in_sizes, int n_in,
                              void* d_out, int out_size, void* d_ws, size_t ws_size,
                              hipStream_t stream) {
    const float* latent0   = (const float*)d_in[0];
    const float* W1        = (const float*)d_in[1];
    const float* b1        = (const float*)d_in[2];
    const float* W2        = (const float*)d_in[3];
    const float* b2        = (const float*)d_in[4];
    const int*   state_seq = (const int*)d_in[5];
    const int*   out_idx   = (const int*)d_in[6];
    float* out = (float*)d_out;

    f16*           W1F = (f16*)d_ws;                                    // 8 MB
    unsigned char* W1Q = (unsigned char*)(W1F + (size_t)NS * NL * NL);  // 4 MB
    f16*           W2F = (f16*)(W1Q + (size_t)NS * NL * NL);            // 1 MB
    unsigned char* W2Q = (unsigned char*)(W2F + (size_t)NS * NO * NL);  // 0.5 MB
    int*           inv = (int*)(W2Q + (size_t)NS * NO * NL);

    const int n4_w1 = NS * NL * NL / 4;   // 1,048,576
    const int n4_w2 = NS * NO * NL / 4;   // 131,072
    split_w_frag<4, 1><<<n4_w1 / 256, 256, 0, stream>>>(W1, W1F, W1Q, n4_w1);
    split_w_frag<1, 0><<<n4_w2 / 256, 256, 0, stream>>>(W2, W2F, W2Q, n4_w2);
    inv_kernel<<<(NS * V_ + 255) / 256, 256, 0, stream>>>(out_idx, inv);

    lalr_main<<<NBLK, 1024, 0, stream>>>(latent0, b1, b2, state_seq, inv,
                                         W1F, W1Q, W2F, W2Q, out);
}